// Round 6
// baseline (225.074 us; speedup 1.0000x reference)
//
#include <hip/hip_runtime.h>
#include <stdint.h>

#define NROWS 65536
#define HD 1024
#define KT 32        // 32 K-tiles of BK=32

typedef __attribute__((ext_vector_type(8))) short bf16x8;   // 8 bf16 in 4 VGPRs
typedef __attribute__((ext_vector_type(16))) float f32x16;  // MFMA 32x32 accumulator

typedef __attribute__((address_space(1))) const unsigned int* gas_ptr;
typedef __attribute__((address_space(3))) unsigned int* las_ptr;

__device__ __forceinline__ unsigned short f2bf(float f) {
  union { float f; uint32_t u; } v; v.f = f;
  uint32_t u = v.u;
  return (unsigned short)((u + 0x7fffu + ((u >> 16) & 1u)) >> 16);  // RNE
}

__device__ __forceinline__ void gl16(const void* g, void* l) {
  __builtin_amdgcn_global_load_lds((gas_ptr)g, (las_ptr)l, 16, 0, 0);
}

// ---------------- prep: W2 fp32 -> bf16, swizzled granules (unchanged layout) ----------------
// W2bf[c][k]; 16B granule g stored at (g&~3) | ((g&3) ^ ((c>>1)&3)).
__global__ void k_w2bf(const float* __restrict__ W2, unsigned short* __restrict__ W2bf) {
  int i = blockIdx.x * 256 + threadIdx.x;   // 131072 threads, 1 granule each
  int c = i >> 7, g = i & 127;
  const float4* s4 = (const float4*)(W2 + (size_t)c * HD + g * 8);
  float4 a = s4[0], b = s4[1];
  uint4 pk;
  pk.x = (uint32_t)f2bf(a.x) | ((uint32_t)f2bf(a.y) << 16);
  pk.y = (uint32_t)f2bf(a.z) | ((uint32_t)f2bf(a.w) << 16);
  pk.z = (uint32_t)f2bf(b.x) | ((uint32_t)f2bf(b.y) << 16);
  pk.w = (uint32_t)f2bf(b.z) | ((uint32_t)f2bf(b.w) << 16);
  int gs = (g & 124) | ((g & 3) ^ ((c >> 1) & 3));
  *(uint4*)(W2bf + (size_t)c * HD + gs * 8) = pk;
}

// ---------------- layer 1 (unchanged): h bf16 [65536][1024], same granule swizzle ----------------
__global__ __launch_bounds__(512) void k_layer1(
    const float* __restrict__ x, const float* __restrict__ W1,
    const float* __restrict__ b1, const float* __restrict__ Wmeta,
    const float* __restrict__ bmeta, unsigned short* __restrict__ h) {
  __shared__ float xs[128 * 12];
  int r0 = blockIdx.x * 128;
  int t = threadIdx.x;
  int j0 = t * 2;
  float w1a = W1[j0], w1b = W1[j0 + 1];
  float b1a = b1[j0], b1b = b1[j0 + 1];
  float wma[10], wmb[10], bma[10], bmb[10];
#pragma unroll
  for (int e = 0; e < 10; e++) {
    float2 wmv = *(const float2*)(Wmeta + e * HD + j0);
    float2 bmv = *(const float2*)(bmeta + e * HD + j0);
    wma[e] = wmv.x; wmb[e] = wmv.y; bma[e] = bmv.x; bmb[e] = bmv.y;
  }
  for (int i = t; i < 128 * 12; i += 512) xs[i] = x[(size_t)r0 * 12 + i];
  __syncthreads();
  int g = j0 >> 3;
  for (int r = 0; r < 128; r++) {
    const float* xr = xs + r * 12;
    float delta = xr[10], phi = xr[11];
    float s1a = 0.f, s1b = 0.f, s2a = 0.f, s2b = 0.f;
#pragma unroll
    for (int e = 0; e < 10; e++) {
      float oh = xr[e];
      s1a = fmaf(oh, wma[e], s1a);
      s1b = fmaf(oh, wmb[e], s1b);
      s2a = fmaf(oh, bma[e], s2a);
      s2b = fmaf(oh, bmb[e], s2b);
    }
    float pa = fmaf(delta, w1a, b1a) + fmaf(phi, s1a, s2a);
    float pb = fmaf(delta, w1b, b1b) + fmaf(phi, s1b, s2b);
    pa = fmaxf(pa, 0.f); pb = fmaxf(pb, 0.f);
    uint32_t pk = (uint32_t)f2bf(pa) | ((uint32_t)f2bf(pb) << 16);
    int rr = r0 + r;
    int gs = (g & 124) | ((g & 3) ^ ((rr >> 1) & 3));
    *(uint32_t*)(h + (size_t)rr * HD + gs * 8 + (j0 & 7)) = pk;
  }
}

// ---------------- layers 2+3: 128x128 tile, 3 blocks/CU, 3-slot prefetch + counted vmcnt ----------------
// grid 4096 (XCD-swizzled) = 512 rt x 8 ct; 256 threads = 4 waves (2x2), wave tile 64x64
// = 2x2 of 32x32x16 bf16 MFMA (acc 64 VGPR). BK=32.
// LDS: 3 slots x (A[128][64B] + B[128][64B]) = 48 KiB; 3 blocks/CU = 144 KiB.
// Per tile T: {8 ds_read_b128 | stage T+2 (4 gl_lds) | lgkmcnt(0) | 8 MFMA |
//   vmcnt(4) | s_barrier}. vmcnt(4): T+2's 4 loads stay in flight, T+1 landed.
// Lead time for a tile's data ~= 1 full tile (~400cy) -> L3 latency hidden.
// Slot safety: stage(T+2) hits slot((T-1)%3); all waves' T-1 reads retired
// (own lgkmcnt(0)) before barrier E(T-1), which precedes any stage in tile T.
__global__ __launch_bounds__(256, 3) void k_gemm(
    const unsigned short* __restrict__ h, const unsigned short* __restrict__ W2bf,
    const float* __restrict__ b2, const float* __restrict__ W3,
    float* __restrict__ partial) {
  __shared__ char lds[49152];   // 3 x 16 KiB slots; epilogue reuses 33792 B
  int tid = threadIdx.x;
  // XCD swizzle: 4096 blocks = 8 XCDs x 512; XCD k gets contiguous logical range.
  int b = (int)blockIdx.x;
  int bx = ((b & 7) << 9) | (b >> 3);
  int rt = bx >> 3, ct = bx & 7;   // 8 consecutive bx share rt -> A-panel L2 reuse
  size_t r0 = (size_t)rt * 128;
  int c0 = ct * 128;
  int w = tid >> 6, lane = tid & 63;
  int wm = w >> 1, wn = w & 1;
  int l31 = lane & 31, hi = lane >> 5;
  int sw = (l31 >> 1) & 3;          // granule swizzle key (row bases are multiples of 32)
  int g0 = (hi ^ sw) << 4;          // k-slice 0 granule byte offset
  int g1 = ((2 + hi) ^ sw) << 4;    // k-slice 1

  f32x16 acc[2][2];
#pragma unroll
  for (int rb = 0; rb < 2; rb++)
#pragma unroll
    for (int cb = 0; cb < 2; cb++)
#pragma unroll
      for (int i = 0; i < 16; i++) acc[rb][cb][i] = 0.f;

  int arow0 = (wm * 64 + l31) * 64;  // A rows: wm*64 + rb*32 + l31 (byte offsets)
  int brow0 = (wn * 64 + l31) * 64;  // B rows: wn*64 + cb*32 + l31

  // stage tile T into slot T%3: A 512 granules + B 512 granules, lane-linear dest.
  auto stage = [&](int T) {
    char* base = lds + (T % 3) * 16384;
#pragma unroll
    for (int q = 0; q < 2; q++) {
      int idx = tid + 256 * q;            // 0..511
      int row = idx >> 2, g4 = idx & 3;   // 4 granules (= BK=32) per row
      gl16(h    + (r0 + row) * (size_t)HD + T * 32 + g4 * 8, base +        (size_t)idx * 16);
      gl16(W2bf + (size_t)(c0 + row) * HD + T * 32 + g4 * 8, base + 8192 + (size_t)idx * 16);
    }
  };

  // prologue: stage tiles 0,1 (8 loads); wait tile 0 (<=4 outstanding); barrier.
  stage(0); stage(1);
  asm volatile("s_waitcnt vmcnt(4)" ::: "memory");
  __builtin_amdgcn_s_barrier();

  for (int T = 0; T < KT; T++) {
    const char* lA = lds + (T % 3) * 16384;
    const char* lB = lA + 8192;
    // 1) read all 8 fragments of this tile
    bf16x8 a00 = *(const bf16x8*)(lA + arow0 + g0);
    bf16x8 a01 = *(const bf16x8*)(lA + arow0 + g1);
    bf16x8 a10 = *(const bf16x8*)(lA + arow0 + 2048 + g0);
    bf16x8 a11 = *(const bf16x8*)(lA + arow0 + 2048 + g1);
    bf16x8 b00 = *(const bf16x8*)(lB + brow0 + g0);
    bf16x8 b01 = *(const bf16x8*)(lB + brow0 + g1);
    bf16x8 b10 = *(const bf16x8*)(lB + brow0 + 2048 + g0);
    bf16x8 b11 = *(const bf16x8*)(lB + brow0 + 2048 + g1);
    // 2) prefetch tile T+2 into slot (T-1)%3
    if (T < KT - 2) stage(T + 2);
    // 3) wait own ds_reads; fence scheduler (rule 18)
    asm volatile("s_waitcnt lgkmcnt(0)" ::: "memory");
    __builtin_amdgcn_sched_barrier(0);
    // 4) MFMA cluster (8)
    __builtin_amdgcn_s_setprio(1);
    acc[0][0] = __builtin_amdgcn_mfma_f32_32x32x16_bf16(a00, b00, acc[0][0], 0, 0, 0);
    acc[0][1] = __builtin_amdgcn_mfma_f32_32x32x16_bf16(a00, b10, acc[0][1], 0, 0, 0);
    acc[1][0] = __builtin_amdgcn_mfma_f32_32x32x16_bf16(a10, b00, acc[1][0], 0, 0, 0);
    acc[1][1] = __builtin_amdgcn_mfma_f32_32x32x16_bf16(a10, b10, acc[1][1], 0, 0, 0);
    acc[0][0] = __builtin_amdgcn_mfma_f32_32x32x16_bf16(a01, b01, acc[0][0], 0, 0, 0);
    acc[0][1] = __builtin_amdgcn_mfma_f32_32x32x16_bf16(a01, b11, acc[0][1], 0, 0, 0);
    acc[1][0] = __builtin_amdgcn_mfma_f32_32x32x16_bf16(a11, b01, acc[1][0], 0, 0, 0);
    acc[1][1] = __builtin_amdgcn_mfma_f32_32x32x16_bf16(a11, b11, acc[1][1], 0, 0, 0);
    __builtin_amdgcn_s_setprio(0);
    // 5) counted vmcnt: tile T+1 landed before the barrier releases (tail: drain)
    if (T == KT - 2) { asm volatile("s_waitcnt vmcnt(0)" ::: "memory"); }
    else             { asm volatile("s_waitcnt vmcnt(4)" ::: "memory"); }
    __builtin_amdgcn_s_barrier();
  }

  // ---- epilogue: v = relu(acc+b2); o = v x W3^T; LDS transpose-reduce ----
  float b2c[2], w30[2], w31[2];
#pragma unroll
  for (int cb = 0; cb < 2; cb++) {
    int c = c0 + wn * 64 + cb * 32 + l31;
    b2c[cb] = b2[c];
    w30[cb] = W3[c];
    w31[cb] = W3[HD + c];
  }
  // padded layout: line = (wm*32+rowf)*2 + wn in [0,128); float2 slot = line*33 + l31
  float2* sE = (float2*)lds;
#pragma unroll
  for (int rb = 0; rb < 2; rb++) {
    __syncthreads();
#pragma unroll
    for (int reg = 0; reg < 16; reg++) {
      float v0 = fmaxf(acc[rb][0][reg] + b2c[0], 0.f);
      float v1 = fmaxf(acc[rb][1][reg] + b2c[1], 0.f);
      float2 o;
      o.x = v0 * w30[0] + v1 * w30[1];
      o.y = v0 * w31[0] + v1 * w31[1];
      int rowf = (reg & 3) + 8 * (reg >> 2) + 4 * hi;   // verified C/D row map
      int line = (wm * 32 + rowf) * 2 + wn;
      sE[line * 33 + l31] = o;
    }
    __syncthreads();
    // reduce: 128 targets (bi 2 x rowf 32 x d 2), 2 threads each (half = wn index)
    int half = tid & 1, tgt = tid >> 1;
    int d = tgt & 1, rowf_t = (tgt >> 1) & 31, bi = tgt >> 6;
    int line0 = (bi * 32 + rowf_t) * 2 + half;
    const float* sf = (const float*)lds;
    float s = 0.f;
#pragma unroll
    for (int j = 0; j < 32; j++) s += sf[(line0 * 33 + j) * 2 + d];
    s += __shfl_xor(s, 1);
    if (half == 0) {
      int row = bi * 64 + rb * 32 + rowf_t;
      partial[(size_t)ct * (NROWS * 2) + (r0 + row) * 2 + d] = s;
    }
  }
}

// ---------------- final: out = b3 + sum over 8 col-tile partials ----------------
__global__ void k_reduce(const float* __restrict__ partial, const float* __restrict__ b3,
                         float* __restrict__ out) {
  int i = blockIdx.x * 256 + threadIdx.x;  // 131072
  float s = b3[i & 1];
#pragma unroll
  for (int ctt = 0; ctt < 8; ctt++) s += partial[(size_t)ctt * 131072 + i];
  out[i] = s;
}

extern "C" void kernel_launch(void* const* d_in, const int* in_sizes, int n_in,
                              void* d_out, int out_size, void* d_ws, size_t ws_size,
                              hipStream_t stream) {
  const float* x     = (const float*)d_in[0];
  const float* W1    = (const float*)d_in[1];
  const float* b1    = (const float*)d_in[2];
  const float* Wmeta = (const float*)d_in[3];
  const float* bmeta = (const float*)d_in[4];
  const float* W2    = (const float*)d_in[5];
  const float* b2    = (const float*)d_in[6];
  const float* W3    = (const float*)d_in[7];
  const float* b3    = (const float*)d_in[8];
  float* out = (float*)d_out;

  char* ws = (char*)d_ws;
  unsigned short* hbuf  = (unsigned short*)ws;                              // 128 MiB
  unsigned short* W2bf  = (unsigned short*)(ws + (size_t)NROWS * HD * 2);   // 2 MiB
  float* partial = (float*)(ws + (size_t)NROWS * HD * 2 + (size_t)HD * HD * 2);  // 4 MiB (8 slices)

  k_w2bf<<<512, 256, 0, stream>>>(W2, W2bf);
  k_layer1<<<512, 512, 0, stream>>>(x, W1, b1, Wmeta, bmeta, hbuf);
  k_gemm<<<4096, 256, 0, stream>>>(hbuf, W2bf, b2, W3, partial);
  k_reduce<<<512, 256, 0, stream>>>(partial, b3, out);
}

// Round 7
// 215.972 us; speedup vs baseline: 1.0421x; 1.0421x over previous
//
#include <hip/hip_runtime.h>
#include <stdint.h>

#define NROWS 65536
#define HD 1024
#define KT 32        // 32 K-tiles of BK=32

typedef __attribute__((ext_vector_type(8))) short bf16x8;  // 8 bf16 in 4 VGPRs
typedef __attribute__((ext_vector_type(4))) float f32x4;   // MFMA 16x16 accumulator

typedef __attribute__((address_space(1))) const unsigned int* gas_ptr;
typedef __attribute__((address_space(3))) unsigned int* las_ptr;

__device__ __forceinline__ unsigned short f2bf(float f) {
  union { float f; uint32_t u; } v; v.f = f;
  uint32_t u = v.u;
  return (unsigned short)((u + 0x7fffu + ((u >> 16) & 1u)) >> 16);  // RNE
}

__device__ __forceinline__ void gl16(const void* g, void* l) {
  __builtin_amdgcn_global_load_lds((gas_ptr)g, (las_ptr)l, 16, 0, 0);
}

// ---------------- prep: W2 fp32 -> bf16, swizzled granules ----------------
// W2bf[c][k]; 16B granule g stored at (g&~3) | ((g&3) ^ (c&3))  [64-B LDS rows]
__global__ void k_w2bf(const float* __restrict__ W2, unsigned short* __restrict__ W2bf) {
  int i = blockIdx.x * 256 + threadIdx.x;   // 131072 threads, 1 granule each
  int c = i >> 7, g = i & 127;
  const float4* s4 = (const float4*)(W2 + (size_t)c * HD + g * 8);
  float4 a = s4[0], b = s4[1];
  uint4 pk;
  pk.x = (uint32_t)f2bf(a.x) | ((uint32_t)f2bf(a.y) << 16);
  pk.y = (uint32_t)f2bf(a.z) | ((uint32_t)f2bf(a.w) << 16);
  pk.z = (uint32_t)f2bf(b.x) | ((uint32_t)f2bf(b.y) << 16);
  pk.w = (uint32_t)f2bf(b.z) | ((uint32_t)f2bf(b.w) << 16);
  int gs = (g & 124) | ((g & 3) ^ (c & 3));
  *(uint4*)(W2bf + (size_t)c * HD + gs * 8) = pk;
}

// ---------------- layer 1: h bf16 [65536][1024], granule swizzle (g&3)^(row&3) ----------------
__global__ __launch_bounds__(512) void k_layer1(
    const float* __restrict__ x, const float* __restrict__ W1,
    const float* __restrict__ b1, const float* __restrict__ Wmeta,
    const float* __restrict__ bmeta, unsigned short* __restrict__ h) {
  __shared__ float xs[128 * 12];
  int r0 = blockIdx.x * 128;
  int t = threadIdx.x;
  int j0 = t * 2;
  float w1a = W1[j0], w1b = W1[j0 + 1];
  float b1a = b1[j0], b1b = b1[j0 + 1];
  float wma[10], wmb[10], bma[10], bmb[10];
#pragma unroll
  for (int e = 0; e < 10; e++) {
    float2 wmv = *(const float2*)(Wmeta + e * HD + j0);
    float2 bmv = *(const float2*)(bmeta + e * HD + j0);
    wma[e] = wmv.x; wmb[e] = wmv.y; bma[e] = bmv.x; bmb[e] = bmv.y;
  }
  for (int i = t; i < 128 * 12; i += 512) xs[i] = x[(size_t)r0 * 12 + i];
  __syncthreads();
  int g = j0 >> 3;
  for (int r = 0; r < 128; r++) {
    const float* xr = xs + r * 12;
    float delta = xr[10], phi = xr[11];
    float s1a = 0.f, s1b = 0.f, s2a = 0.f, s2b = 0.f;
#pragma unroll
    for (int e = 0; e < 10; e++) {
      float oh = xr[e];
      s1a = fmaf(oh, wma[e], s1a);
      s1b = fmaf(oh, wmb[e], s1b);
      s2a = fmaf(oh, bma[e], s2a);
      s2b = fmaf(oh, bmb[e], s2b);
    }
    float pa = fmaf(delta, w1a, b1a) + fmaf(phi, s1a, s2a);
    float pb = fmaf(delta, w1b, b1b) + fmaf(phi, s1b, s2b);
    pa = fmaxf(pa, 0.f); pb = fmaxf(pb, 0.f);
    uint32_t pk = (uint32_t)f2bf(pa) | ((uint32_t)f2bf(pb) << 16);
    int rr = r0 + r;
    int gs = (g & 124) | ((g & 3) ^ (rr & 3));
    *(uint32_t*)(h + (size_t)rr * HD + gs * 8 + (j0 & 7)) = pk;
  }
}

// ---------------- layers 2+3: 256x128 block, 4 waves of 128x64, 16x16x32 MFMA ----------------
// grid 2048 (XCD-swizzled) = 256 rt x 8 ct; 256 threads = 4 waves (2wm x 2wn),
// wave tile 128x64 = 8x4 fragments of 16x16x32 (acc = 8x4 f32x4 = 128 VGPR).
// Reads per wave per BK=32 tile: 12 ds_read_b128 for 32 MFMA (vs 8:8 before) —
// device LDS traffic 3.2 GB (46us) < MFMA floor (55us): matrix-dominant.
// LDS: 3 slots x (A[256][32] 16KB + B[128][32] 8KB) = 72 KiB -> 2 blocks/CU.
// Per tile: {8 ds_read | stage T+2 (6 gl_lds) | lgkm0 | 16 MFMA (fm0-3) |
//   4 ds_read (fm4-7, B reused) | lgkm0 | 16 MFMA | vmcnt(6) | barrier}.
// Slot safety: stage(T+2) hits slot (T-1)%3 after E(T-1): all T-1 reads drained.
__global__ __launch_bounds__(256, 2) void k_gemm(
    const unsigned short* __restrict__ h, const unsigned short* __restrict__ W2bf,
    const float* __restrict__ b2, const float* __restrict__ W3,
    float* __restrict__ partial) {
  __shared__ char lds[73728];   // 3 x 24 KiB slots; epilogue reuses 4 KiB
  int tid = threadIdx.x;
  // XCD swizzle: 2048 blocks = 8 XCDs x 256; consecutive logical bx share rt.
  int b = (int)blockIdx.x;
  int bx = ((b & 7) << 8) | (b >> 3);
  int rt = bx >> 3, ct = bx & 7;
  size_t r0 = (size_t)rt * 256;
  int c0 = ct * 128;
  int w = tid >> 6, lane = tid & 63;
  int wm = w >> 1, wn = w & 1;
  int l15 = lane & 15, l4 = lane >> 4;
  int gsw = ((l4 ^ (l15 & 3)) << 4);          // swizzled granule byte, per-thread const
  int aBase = (wm * 128 + l15) * 64 + gsw;    // + fm*1024
  int bBase = (wn * 64 + l15) * 64 + gsw;     // + fn*1024

  f32x4 acc[8][4];
#pragma unroll
  for (int fm = 0; fm < 8; fm++)
#pragma unroll
    for (int fn = 0; fn < 4; fn++)
#pragma unroll
      for (int i = 0; i < 4; i++) acc[fm][fn][i] = 0.f;

  // stage tile T into slot T%3 (6 gl_lds/thread; dest lane-linear)
  auto stage = [&](int T) {
    char* base = lds + (T % 3) * 24576;
    const unsigned short* hs = h + r0 * HD + T * 32;
    const unsigned short* ws = W2bf + (size_t)c0 * HD + T * 32;
#pragma unroll
    for (int q = 0; q < 4; q++) {           // A: 1024 granules
      int idx = tid + 256 * q;
      int row = idx >> 2, g4 = idx & 3;
      gl16(hs + (size_t)row * HD + g4 * 8, base + (size_t)idx * 16);
    }
#pragma unroll
    for (int q = 0; q < 2; q++) {           // B: 512 granules
      int idx = tid + 256 * q;
      int row = idx >> 2, g4 = idx & 3;
      gl16(ws + (size_t)row * HD + g4 * 8, base + 16384 + (size_t)idx * 16);
    }
  };

  // prologue: stage tiles 0,1 (12 loads); wait tile 0 (<=6 outstanding); barrier.
  stage(0); stage(1);
  asm volatile("s_waitcnt vmcnt(6)" ::: "memory");
  __builtin_amdgcn_s_barrier();

  for (int T = 0; T < KT; T++) {
    const char* sA = lds + (T % 3) * 24576;
    const char* sB = sA + 16384;
    bf16x8 aF[4], bF[4];
#pragma unroll
    for (int i = 0; i < 4; i++) {
      aF[i] = *(const bf16x8*)(sA + aBase + i * 1024);
      bF[i] = *(const bf16x8*)(sB + bBase + i * 1024);
    }
    if (T < KT - 2) stage(T + 2);
    asm volatile("s_waitcnt lgkmcnt(0)" ::: "memory");
    __builtin_amdgcn_sched_barrier(0);
    __builtin_amdgcn_s_setprio(1);
#pragma unroll
    for (int fm = 0; fm < 4; fm++)
#pragma unroll
      for (int fn = 0; fn < 4; fn++)
        acc[fm][fn] = __builtin_amdgcn_mfma_f32_16x16x32_bf16(aF[fm], bF[fn], acc[fm][fn], 0, 0, 0);
    __builtin_amdgcn_s_setprio(0);
#pragma unroll
    for (int i = 0; i < 4; i++)
      aF[i] = *(const bf16x8*)(sA + aBase + (4 + i) * 1024);
    asm volatile("s_waitcnt lgkmcnt(0)" ::: "memory");
    __builtin_amdgcn_sched_barrier(0);
    __builtin_amdgcn_s_setprio(1);
#pragma unroll
    for (int fm = 0; fm < 4; fm++)
#pragma unroll
      for (int fn = 0; fn < 4; fn++)
        acc[4 + fm][fn] = __builtin_amdgcn_mfma_f32_16x16x32_bf16(aF[fm], bF[fn], acc[4 + fm][fn], 0, 0, 0);
    __builtin_amdgcn_s_setprio(0);
    // counted vmcnt: tile T+1 landed before barrier releases; drain at the tail
    if (T == KT - 2)      { asm volatile("s_waitcnt vmcnt(0)" ::: "memory"); }
    else if (T < KT - 2)  { asm volatile("s_waitcnt vmcnt(6)" ::: "memory"); }
    __builtin_amdgcn_s_barrier();
  }

  // ---- epilogue: v = relu(acc+b2); o = v x W3^T; 16-lane shfl reduce; cross-wn via LDS ----
  float b2c[4], w30[4], w31[4];
#pragma unroll
  for (int fn = 0; fn < 4; fn++) {
    int c = c0 + wn * 64 + fn * 16 + l15;
    b2c[fn] = b2[c];
    w30[fn] = W3[c];
    w31[fn] = W3[HD + c];
  }
  float* sOut = (float*)lds;  // [2 wn][256 rows][2]
#pragma unroll
  for (int fm = 0; fm < 8; fm++) {
#pragma unroll
    for (int reg = 0; reg < 4; reg++) {
      float o0 = 0.f, o1 = 0.f;
#pragma unroll
      for (int fn = 0; fn < 4; fn++) {
        float v = fmaxf(acc[fm][fn][reg] + b2c[fn], 0.f);
        o0 = fmaf(v, w30[fn], o0);
        o1 = fmaf(v, w31[fn], o1);
      }
#pragma unroll
      for (int m = 1; m <= 8; m <<= 1) {  // reduce over l15 (16 cols)
        o0 += __shfl_xor(o0, m);
        o1 += __shfl_xor(o1, m);
      }
      if (l15 == 0) {
        int row = wm * 128 + fm * 16 + l4 * 4 + reg;  // C/D row map (m89): (l>>4)*4+reg
        sOut[(wn * 256 + row) * 2 + 0] = o0;
        sOut[(wn * 256 + row) * 2 + 1] = o1;
      }
    }
  }
  __syncthreads();
#pragma unroll
  for (int q = 0; q < 2; q++) {
    int j = tid + q * 256;    // 512 values = 256 rows x 2 outputs
    float s = sOut[j] + sOut[512 + j];
    partial[(size_t)ct * (NROWS * 2) + r0 * 2 + j] = s;
  }
}

// ---------------- final: out = b3 + sum over 8 col-tile partials ----------------
__global__ void k_reduce(const float* __restrict__ partial, const float* __restrict__ b3,
                         float* __restrict__ out) {
  int i = blockIdx.x * 256 + threadIdx.x;  // 131072
  float s = b3[i & 1];
#pragma unroll
  for (int ctt = 0; ctt < 8; ctt++) s += partial[(size_t)ctt * 131072 + i];
  out[i] = s;
}

extern "C" void kernel_launch(void* const* d_in, const int* in_sizes, int n_in,
                              void* d_out, int out_size, void* d_ws, size_t ws_size,
                              hipStream_t stream) {
  const float* x     = (const float*)d_in[0];
  const float* W1    = (const float*)d_in[1];
  const float* b1    = (const float*)d_in[2];
  const float* Wmeta = (const float*)d_in[3];
  const float* bmeta = (const float*)d_in[4];
  const float* W2    = (const float*)d_in[5];
  const float* b2    = (const float*)d_in[6];
  const float* W3    = (const float*)d_in[7];
  const float* b3    = (const float*)d_in[8];
  float* out = (float*)d_out;

  char* ws = (char*)d_ws;
  unsigned short* hbuf  = (unsigned short*)ws;                              // 128 MiB
  unsigned short* W2bf  = (unsigned short*)(ws + (size_t)NROWS * HD * 2);   // 2 MiB
  float* partial = (float*)(ws + (size_t)NROWS * HD * 2 + (size_t)HD * HD * 2);  // 4 MiB (8 slices)

  k_w2bf<<<512, 256, 0, stream>>>(W2, W2bf);
  k_layer1<<<512, 512, 0, stream>>>(x, W1, b1, Wmeta, bmeta, hbuf);
  k_gemm<<<2048, 256, 0, stream>>>(hbuf, W2bf, b2, W3, partial);
  k_reduce<<<512, 256, 0, stream>>>(partial, b3, out);
}